// Round 1
// baseline (103.325 us; speedup 1.0000x reference)
//
#include <hip/hip_runtime.h>

#define NI 100000
#define NJ 50000
#define KD 25
#define SI 8192
#define SJ 4096
#define NE 1000000
#define EPSC 1e-6f

#define NBI ((NI + 255) / 256)   // 391
#define NBJ ((NJ + 255) / 256)   // 196
#define NBZCI 32                 // 32*256 = 8192 samples
#define NBZCJ 16                 // 16*256 = 4096 samples
#define NBD 256                  // dense: 256 blocks * 32 rows = 8192 rows
#define NBS 512                  // sparse blocks

// workspace layout (float offsets)
#define W_CSI 0                  // colsum_i[25]
#define W_CSJ 32                 // colsum_j[25]
#define W_ZCI 64                 // ZCraw_i[625]
#define W_ZCJ 704                // ZCraw_j[625]
#define W_AZCI 1344              // AZC_i[50]
#define W_AZCJ 1408              // AZC_j[50]
#define W_Z1 1472
#define W_Z2 1473
#define W_PAI 1536               // points_i[2*NI]
#define W_PAJ (W_PAI + 2 * NI)   // points_j[2*NJ]

__global__ void k_init(float* __restrict__ ws) {
    int t = blockIdx.x * 256 + threadIdx.x;
    if (t < 1536) ws[t] = 0.f;
}

__device__ __forceinline__ void softmax_col(const float* __restrict__ Z, int N, int i,
                                            float* z) {
    float m = -1e30f;
#pragma unroll
    for (int k = 0; k < KD; k++) { z[k] = Z[k * N + i]; m = fmaxf(m, z[k]); }
    float s = 0.f;
#pragma unroll
    for (int k = 0; k < KD; k++) { z[k] = __expf(z[k] - m); s += z[k]; }
    float inv = 1.f / s;
#pragma unroll
    for (int k = 0; k < KD; k++) z[k] *= inv;
}

// ---- colsum: colsum[k] = sum_i softmax(Z)[k,i] * sigmoid(G[i,k]) ----
__device__ void colsum_pass(const float* __restrict__ Z, const float* __restrict__ G,
                            float* __restrict__ colsum, int N, int blk) {
    int i = blk * 256 + threadIdx.x;
    float t[KD];
    if (i < N) {
        float z[KD];
        softmax_col(Z, N, i, z);
#pragma unroll
        for (int k = 0; k < KD; k++) {
            float g = G[i * KD + k];
            t[k] = z[k] / (1.f + __expf(-g));
        }
    } else {
#pragma unroll
        for (int k = 0; k < KD; k++) t[k] = 0.f;
    }
    __shared__ float part[KD][4];
    int lane = threadIdx.x & 63, wv = threadIdx.x >> 6;
#pragma unroll
    for (int k = 0; k < KD; k++) {
        float v = t[k];
        for (int o = 32; o > 0; o >>= 1) v += __shfl_down(v, o);
        if (lane == 0) part[k][wv] = v;
    }
    __syncthreads();
    if (threadIdx.x < KD) {
        float v = part[threadIdx.x][0] + part[threadIdx.x][1] +
                  part[threadIdx.x][2] + part[threadIdx.x][3];
        atomicAdd(&colsum[threadIdx.x], v);
    }
}

__global__ void __launch_bounds__(256) k_colsum(const float* __restrict__ Zi,
                                                const float* __restrict__ Zj,
                                                const float* __restrict__ Gi,
                                                const float* __restrict__ Gj,
                                                float* __restrict__ ws) {
    int b = blockIdx.x;
    if (b < NBI) colsum_pass(Zi, Gi, ws + W_CSI, NI, b);
    else         colsum_pass(Zj, Gj, ws + W_CSJ, NJ, b - NBI);
}

// ---- ZCraw[a,b] = sum_s z[a,s]*z[b,s]*sig(g[s,b]) over sampled columns ----
__device__ void zc_pass(const float* __restrict__ Z, const float* __restrict__ G,
                        const int* __restrict__ samp, float* __restrict__ zcraw,
                        int N, int blk) {
    __shared__ float zb[256][KD + 1];
    __shared__ float sb[256][KD + 1];
    int tid = threadIdx.x;
    int idx = samp[blk * 256 + tid];
    float z[KD];
    softmax_col(Z, N, idx, z);
#pragma unroll
    for (int k = 0; k < KD; k++) {
        zb[tid][k] = z[k];
        float g = G[idx * KD + k];
        sb[tid][k] = 1.f / (1.f + __expf(-g));
    }
    __syncthreads();
    for (int p = tid; p < KD * KD; p += 256) {
        int a = p / KD, bb = p % KD;
        float acc = 0.f;
        for (int s = 0; s < 256; s++) acc += zb[s][a] * zb[s][bb] * sb[s][bb];
        atomicAdd(&zcraw[p], acc);
    }
}

__global__ void __launch_bounds__(256) k_zc(const float* __restrict__ Zi,
                                            const float* __restrict__ Zj,
                                            const float* __restrict__ Gi,
                                            const float* __restrict__ Gj,
                                            const int* __restrict__ si,
                                            const int* __restrict__ sj,
                                            float* __restrict__ ws) {
    int b = blockIdx.x;
    if (b < NBZCI) zc_pass(Zi, Gi, si, ws + W_ZCI, NI, b);
    else           zc_pass(Zj, Gj, sj, ws + W_ZCJ, NJ, b - NBZCI);
}

// ---- AZC[d,b] = (sum_a A[d,a]*ZCraw[a,b]) / colsum[b]  (2x25, both sides) ----
__global__ void k_azc(const float* __restrict__ Ai, const float* __restrict__ Aj,
                      float* __restrict__ ws) {
    int t = threadIdx.x;
    if (t < 2 * KD) {
        int d = t / KD, bcol = t % KD;
        float acc = 0.f;
#pragma unroll
        for (int a = 0; a < KD; a++) acc += Ai[d * KD + a] * ws[W_ZCI + a * KD + bcol];
        ws[W_AZCI + t] = acc / ws[W_CSI + bcol];
    } else if (t >= 64 && t < 64 + 2 * KD) {
        int tt = t - 64;
        int d = tt / KD, bcol = tt % KD;
        float acc = 0.f;
#pragma unroll
        for (int a = 0; a < KD; a++) acc += Aj[d * KD + a] * ws[W_ZCJ + a * KD + bcol];
        ws[W_AZCJ + tt] = acc / ws[W_CSJ + bcol];
    }
}

// ---- PA[i] = AZC @ softmax(Z[:,i])   (2-D point per node) ----
__global__ void __launch_bounds__(256) k_pa(const float* __restrict__ Zi,
                                            const float* __restrict__ Zj,
                                            float* __restrict__ ws) {
    __shared__ float azc[2 * KD];
    int b = blockIdx.x;
    const float* Z; float* PA; int N; int i0; const float* src;
    if (b < NBI) { Z = Zi; PA = ws + W_PAI; N = NI; src = ws + W_AZCI; i0 = b * 256; }
    else { Z = Zj; PA = ws + W_PAJ; N = NJ; src = ws + W_AZCJ; i0 = (b - NBI) * 256; }
    if (threadIdx.x < 2 * KD) azc[threadIdx.x] = src[threadIdx.x];
    __syncthreads();
    int i = i0 + threadIdx.x;
    if (i < N) {
        float z[KD];
        softmax_col(Z, N, i, z);
        float x = 0.f, y = 0.f;
#pragma unroll
        for (int k = 0; k < KD; k++) { x += azc[k] * z[k]; y += azc[KD + k] * z[k]; }
        PA[2 * i] = x;
        PA[2 * i + 1] = y;
    }
}

__device__ __forceinline__ float block_sum(float v) {
    __shared__ float part[4];
    int lane = threadIdx.x & 63, wv = threadIdx.x >> 6;
#pragma unroll
    for (int o = 32; o > 0; o >>= 1) v += __shfl_down(v, o);
    if (lane == 0) part[wv] = v;
    __syncthreads();
    float r = 0.f;
    if (threadIdx.x == 0) r = part[0] + part[1] + part[2] + part[3];
    return r;
}

// ---- dense 8192x4096 pairwise sum + sparse 1e6-edge sum ----
__global__ void __launch_bounds__(256) k_sums(const float* __restrict__ beta,
                                              const float* __restrict__ gamma,
                                              const int* __restrict__ si,
                                              const int* __restrict__ sj,
                                              const int* __restrict__ spi,
                                              const int* __restrict__ spj,
                                              float* __restrict__ ws) {
    int b = blockIdx.x;
    int tid = threadIdx.x;
    const float2* PAi = (const float2*)(ws + W_PAI);
    const float2* PAj = (const float2*)(ws + W_PAJ);
    if (b < NBD) {
        // dense: 32 rows per block, each thread owns 16 j-columns in registers
        __shared__ float rx[32], ry[32], rb[32];
        if (tid < 32) {
            int s = b * 32 + tid;
            int ii = si[s];
            float2 p = PAi[ii];
            rx[tid] = p.x; ry[tid] = p.y; rb[tid] = beta[ii];
        }
        __syncthreads();
        float jx[16], jy[16], jg[16];
#pragma unroll
        for (int q = 0; q < 16; q++) {
            int j = q * 256 + tid;
            int jj = sj[j];
            float2 p = PAj[jj];
            jx[q] = p.x; jy[q] = p.y; jg[q] = gamma[jj];
        }
        float acc = 0.f;
        for (int r = 0; r < 32; r++) {
            float px = rx[r], py = ry[r], bb = rb[r];
            int dq = (b * 32 + r) - tid;  // diagonal when q*256 == dq
#pragma unroll
            for (int q = 0; q < 16; q++) {
                float dx = px - jx[q] + EPSC;
                float dy = py - jy[q] + EPSC;
                float dist = sqrtf(dx * dx + dy * dy);
                float v = __expf(bb + jg[q] - dist);
                acc += (q * 256 == dq) ? 0.f : v;
            }
        }
        float r = block_sum(acc);
        if (tid == 0) atomicAdd(&ws[W_Z1], r);
    } else {
        int sb = b - NBD;
        float acc = 0.f;
        for (int e = sb * 256 + tid; e < NE; e += NBS * 256) {
            int a = spi[e], c = spj[e];
            float2 pi = PAi[a], pj = PAj[c];
            float dx = pi.x - pj.x + EPSC;
            float dy = pi.y - pj.y + EPSC;
            float d = sqrtf(dx * dx + dy * dy);
            acc += beta[a] + beta[c] - d;
        }
        float r = block_sum(acc);
        if (tid == 0) atomicAdd(&ws[W_Z2], r);
    }
}

__global__ void k_fin(const float* __restrict__ ws, float* __restrict__ out) {
    // 0.5 * e * e = 3.694528049465325
    out[0] = ws[W_Z2] - 3.6945280494653252f * ws[W_Z1];
}

extern "C" void kernel_launch(void* const* d_in, const int* in_sizes, int n_in,
                              void* d_out, int out_size, void* d_ws, size_t ws_size,
                              hipStream_t stream) {
    const float* beta  = (const float*)d_in[0];
    const float* gamma = (const float*)d_in[1];
    const float* Ai    = (const float*)d_in[2];
    const float* Aj    = (const float*)d_in[3];
    const float* Zi    = (const float*)d_in[4];
    const float* Zj    = (const float*)d_in[5];
    const float* Gi    = (const float*)d_in[6];
    const float* Gj    = (const float*)d_in[7];
    const int* si  = (const int*)d_in[8];
    const int* sj  = (const int*)d_in[9];
    const int* spi = (const int*)d_in[10];
    const int* spj = (const int*)d_in[11];
    float* ws  = (float*)d_ws;
    float* out = (float*)d_out;

    k_init<<<6, 256, 0, stream>>>(ws);
    k_colsum<<<NBI + NBJ, 256, 0, stream>>>(Zi, Zj, Gi, Gj, ws);
    k_zc<<<NBZCI + NBZCJ, 256, 0, stream>>>(Zi, Zj, Gi, Gj, si, sj, ws);
    k_azc<<<1, 128, 0, stream>>>(Ai, Aj, ws);
    k_pa<<<NBI + NBJ, 256, 0, stream>>>(Zi, Zj, ws);
    k_sums<<<NBD + NBS, 256, 0, stream>>>(beta, gamma, si, sj, spi, spj, ws);
    k_fin<<<1, 1, 0, stream>>>(ws, out);
}

// Round 2
// 79.059 us; speedup vs baseline: 1.3069x; 1.3069x over previous
//
#include <hip/hip_runtime.h>

#define NI 100000
#define NJ 50000
#define KD 25
#define SI 8192
#define SJ 4096
#define NE 1000000
#define EPSC 1e-6f

#define NBI ((NI + 255) / 256)   // 391
#define NBJ ((NJ + 255) / 256)   // 196
#define NZI (SI / 64)            // 128 zc blocks, 64 samples each
#define NZJ (SJ / 64)            // 64
#define NDB 1024                 // dense: 512 row-groups x 2 col-halves
#define NSB 1024                 // sparse: 1024*256 threads, 4 edges each
#define NGB 16                   // diag: 16*256 = 4096

// workspace layout (float offsets)
#define W_CSI 0
#define W_CSJ 32
#define W_ZCI 64
#define W_ZCJ 704
#define W_Z1 1472
#define W_Z2 1473
#define W_QI 2048                 // float4[NI]  (x, y, beta, 0)
#define W_QJ (W_QI + 4 * NI)      // float4[NJ]  (x-eps, y-eps, beta, gamma)

__global__ void k_init(float* __restrict__ ws) {
    int t = blockIdx.x * 256 + threadIdx.x;
    if (t < 1536) ws[t] = 0.f;
}

__device__ __forceinline__ void softmax_col(const float* __restrict__ Z, int N, int i,
                                            float* z) {
    float m = -1e30f;
#pragma unroll
    for (int k = 0; k < KD; k++) { z[k] = Z[k * N + i]; m = fmaxf(m, z[k]); }
    float s = 0.f;
#pragma unroll
    for (int k = 0; k < KD; k++) { z[k] = __expf(z[k] - m); s += z[k]; }
    float inv = 1.f / s;
#pragma unroll
    for (int k = 0; k < KD; k++) z[k] *= inv;
}

// ---- colsum[k] = sum_i softmax(Z)[k,i] * sigmoid(G[i,k]) ----
__device__ void colsum_pass(const float* __restrict__ Z, const float* __restrict__ G,
                            float* __restrict__ colsum, int N, int blk) {
    int i = blk * 256 + threadIdx.x;
    float z[KD];
    if (i < N) {
        softmax_col(Z, N, i, z);
#pragma unroll
        for (int k = 0; k < KD; k++) {
            float g = G[i * KD + k];
            z[k] = z[k] / (1.f + __expf(-g));
        }
    } else {
#pragma unroll
        for (int k = 0; k < KD; k++) z[k] = 0.f;
    }
    __shared__ float part[KD][4];
    int lane = threadIdx.x & 63, wv = threadIdx.x >> 6;
#pragma unroll
    for (int k = 0; k < KD; k++) {
        float v = z[k];
        for (int o = 32; o > 0; o >>= 1) v += __shfl_down(v, o);
        if (lane == 0) part[k][wv] = v;
    }
    __syncthreads();
    if (threadIdx.x < KD) {
        float v = part[threadIdx.x][0] + part[threadIdx.x][1] +
                  part[threadIdx.x][2] + part[threadIdx.x][3];
        atomicAdd(&colsum[threadIdx.x], v);
    }
}

// ---- ZCraw[a,b] = sum_s z[a,s] * (z[b,s]*sig(g[s,b]))  (64 samples/block) ----
__device__ void zc_pass(const float* __restrict__ Z, const float* __restrict__ G,
                        const int* __restrict__ samp, float* __restrict__ zcraw,
                        int N, int blk) {
    __shared__ float zb[64][KD + 1];
    __shared__ float zs[64][KD + 1];
    int tid = threadIdx.x;
    if (tid < 64) {
        int idx = samp[blk * 64 + tid];
        float z[KD];
        softmax_col(Z, N, idx, z);
#pragma unroll
        for (int k = 0; k < KD; k++) {
            zb[tid][k] = z[k];
            float g = G[idx * KD + k];
            zs[tid][k] = z[k] / (1.f + __expf(-g));
        }
    }
    __syncthreads();
    for (int p = tid; p < KD * KD; p += 256) {
        int a = p / KD, bb = p % KD;
        float acc = 0.f;
#pragma unroll 8
        for (int s = 0; s < 64; s++) acc += zb[s][a] * zs[s][bb];
        atomicAdd(&zcraw[p], acc);
    }
}

__global__ void __launch_bounds__(256) k_s1(const float* __restrict__ Zi,
                                            const float* __restrict__ Zj,
                                            const float* __restrict__ Gi,
                                            const float* __restrict__ Gj,
                                            const int* __restrict__ si,
                                            const int* __restrict__ sj,
                                            float* __restrict__ ws) {
    int b = blockIdx.x;
    if (b < NBI)                  colsum_pass(Zi, Gi, ws + W_CSI, NI, b);
    else if (b < NBI + NBJ)       colsum_pass(Zj, Gj, ws + W_CSJ, NJ, b - NBI);
    else if (b < NBI + NBJ + NZI) zc_pass(Zi, Gi, si, ws + W_ZCI, NI, b - NBI - NBJ);
    else                          zc_pass(Zj, Gj, sj, ws + W_ZCJ, NJ, b - NBI - NBJ - NZI);
}

// ---- per-node point + packed side data ----
__global__ void __launch_bounds__(256) k_pa(const float* __restrict__ Zi,
                                            const float* __restrict__ Zj,
                                            const float* __restrict__ beta,
                                            const float* __restrict__ gamma,
                                            const float* __restrict__ Ai,
                                            const float* __restrict__ Aj,
                                            float* __restrict__ ws) {
    __shared__ float azc[64];
    int b = blockIdx.x;
    bool isI = b < NBI;
    const float* A  = isI ? Ai : Aj;
    const float* ZC = ws + (isI ? W_ZCI : W_ZCJ);
    const float* CS = ws + (isI ? W_CSI : W_CSJ);
    if (threadIdx.x < 2 * KD) {
        int d = threadIdx.x / KD, c = threadIdx.x % KD;
        float acc = 0.f;
#pragma unroll
        for (int a = 0; a < KD; a++) acc += A[d * KD + a] * ZC[a * KD + c];
        azc[threadIdx.x] = acc / CS[c];
    }
    __syncthreads();
    const float* Z = isI ? Zi : Zj;
    int N = isI ? NI : NJ;
    int i = (isI ? b : b - NBI) * 256 + threadIdx.x;
    if (i < N) {
        float z[KD];
        softmax_col(Z, N, i, z);
        float x = 0.f, y = 0.f;
#pragma unroll
        for (int k = 0; k < KD; k++) { x += azc[k] * z[k]; y += azc[KD + k] * z[k]; }
        float4* Q = (float4*)(ws + (isI ? W_QI : W_QJ));
        if (isI) Q[i] = make_float4(x, y, beta[i], 0.f);
        else     Q[i] = make_float4(x - EPSC, y - EPSC, beta[i], gamma[i]);
    }
}

__device__ __forceinline__ void block_sum_atomic(float v, float* dst, float sign) {
    __shared__ float part[4];
    int lane = threadIdx.x & 63, wv = threadIdx.x >> 6;
#pragma unroll
    for (int o = 32; o > 0; o >>= 1) v += __shfl_down(v, o);
    if (lane == 0) part[wv] = v;
    __syncthreads();
    if (threadIdx.x == 0)
        atomicAdd(dst, sign * (part[0] + part[1] + part[2] + part[3]));
}

__global__ void __launch_bounds__(256) k_sums(const int* __restrict__ si,
                                              const int* __restrict__ sj,
                                              const int* __restrict__ spi,
                                              const int* __restrict__ spj,
                                              float* __restrict__ ws) {
    const float4* Qi = (const float4*)(ws + W_QI);
    const float4* Qj = (const float4*)(ws + W_QJ);
    int b = blockIdx.x, tid = threadIdx.x;
    if (b < NDB) {
        // dense 16 rows x 2048 cols; 8 cols/thread in regs, full-sum (diag removed later)
        __shared__ float4 rows[16];
        int r0 = (b >> 1) * 16, c0 = (b & 1) * 2048;
        if (tid < 16) rows[tid] = Qi[si[r0 + tid]];
        float cx[8], cy[8], cg[8];
#pragma unroll
        for (int q = 0; q < 8; q++) {
            int jj = sj[c0 + q * 256 + tid];
            float4 p = Qj[jj];
            cx[q] = p.x; cy[q] = p.y; cg[q] = p.w;
        }
        __syncthreads();
        float acc = 0.f;
        for (int r = 0; r < 16; r++) {
            float4 R = rows[r];
#pragma unroll
            for (int q = 0; q < 8; q++) {
                float dx = R.x - cx[q];
                float dy = R.y - cy[q];
                float d2 = fmaf(dy, dy, dx * dx);
                float dist = sqrtf(d2);
                acc += __expf(R.z + cg[q] - dist);
            }
        }
        block_sum_atomic(acc, &ws[W_Z1], 1.f);
    } else if (b < NDB + NSB) {
        int g4 = (b - NDB) * 256 + tid;
        float acc = 0.f;
        if (g4 < NE / 4) {
            int4 ia = ((const int4*)spi)[g4];
            int4 ja = ((const int4*)spj)[g4];
            float4 a0 = Qi[ia.x], a1 = Qi[ia.y], a2 = Qi[ia.z], a3 = Qi[ia.w];
            float4 b0 = Qj[ja.x], b1 = Qj[ja.y], b2 = Qj[ja.z], b3 = Qj[ja.w];
            float dx, dy;
            dx = a0.x - b0.x; dy = a0.y - b0.y;
            acc += a0.z + b0.z - sqrtf(fmaf(dy, dy, dx * dx));
            dx = a1.x - b1.x; dy = a1.y - b1.y;
            acc += a1.z + b1.z - sqrtf(fmaf(dy, dy, dx * dx));
            dx = a2.x - b2.x; dy = a2.y - b2.y;
            acc += a2.z + b2.z - sqrtf(fmaf(dy, dy, dx * dx));
            dx = a3.x - b3.x; dy = a3.y - b3.y;
            acc += a3.z + b3.z - sqrtf(fmaf(dy, dy, dx * dx));
        }
        block_sum_atomic(acc, &ws[W_Z2], 1.f);
    } else {
        // diagonal pairs (s,s), s in [0,4096): subtract from Z1
        int s = (b - NDB - NSB) * 256 + tid;
        float4 qi = Qi[si[s]];
        float4 qj = Qj[sj[s]];
        float dx = qi.x - qj.x, dy = qi.y - qj.y;
        float v = __expf(qi.z + qj.w - sqrtf(fmaf(dy, dy, dx * dx)));
        block_sum_atomic(v, &ws[W_Z1], -1.f);
    }
}

__global__ void k_fin(const float* __restrict__ ws, float* __restrict__ out) {
    // 0.5 * e * e
    out[0] = ws[W_Z2] - 3.6945280494653252f * ws[W_Z1];
}

extern "C" void kernel_launch(void* const* d_in, const int* in_sizes, int n_in,
                              void* d_out, int out_size, void* d_ws, size_t ws_size,
                              hipStream_t stream) {
    const float* beta  = (const float*)d_in[0];
    const float* gamma = (const float*)d_in[1];
    const float* Ai    = (const float*)d_in[2];
    const float* Aj    = (const float*)d_in[3];
    const float* Zi    = (const float*)d_in[4];
    const float* Zj    = (const float*)d_in[5];
    const float* Gi    = (const float*)d_in[6];
    const float* Gj    = (const float*)d_in[7];
    const int* si  = (const int*)d_in[8];
    const int* sj  = (const int*)d_in[9];
    const int* spi = (const int*)d_in[10];
    const int* spj = (const int*)d_in[11];
    float* ws  = (float*)d_ws;
    float* out = (float*)d_out;

    k_init<<<6, 256, 0, stream>>>(ws);
    k_s1<<<NBI + NBJ + NZI + NZJ, 256, 0, stream>>>(Zi, Zj, Gi, Gj, si, sj, ws);
    k_pa<<<NBI + NBJ, 256, 0, stream>>>(Zi, Zj, beta, gamma, Ai, Aj, ws);
    k_sums<<<NDB + NSB + NGB, 256, 0, stream>>>(si, sj, spi, spj, ws);
    k_fin<<<1, 1, 0, stream>>>(ws, out);
}

// Round 3
// 71.962 us; speedup vs baseline: 1.4358x; 1.0986x over previous
//
#include <hip/hip_runtime.h>

#define NI 100000
#define NJ 50000
#define KD 25
#define SI 8192
#define SJ 4096
#define NE 1000000
#define EPSC 1e-6f
#define LOG2E 1.4426950408889634f
#define HALF_E2 3.6945280494653252f   // 0.5 * e * e

#define NBI ((NI + 255) / 256)   // 391
#define NBJ ((NJ + 255) / 256)   // 196
#define NZI (SI / 64)            // 128
#define NZJ (SJ / 64)            // 64
#define NDB 1024                 // dense: 512 row-groups x 2 col-halves
#define NSB 1024                 // sparse
#define NGB 16                   // diag

// workspace layout (float offsets)
#define W_CSI 0
#define W_CSJ 32
#define W_ZCI 64
#define W_ZCJ 704
#define W_QI 2048                 // float4[NI]  (x, y, beta, 0)
#define W_QJ (W_QI + 4 * NI)      // float4[NJ]  (x-eps, y-eps, beta, gamma)

__device__ __forceinline__ float fexp2(float x) { return __builtin_amdgcn_exp2f(x); }
__device__ __forceinline__ float fsqrt(float x) { return __builtin_amdgcn_sqrtf(x); }
__device__ __forceinline__ float frcp(float x)  { return __builtin_amdgcn_rcpf(x); }
__device__ __forceinline__ float fsig(float g)  { return frcp(1.f + fexp2(-g * LOG2E)); }

__global__ void k_init(float* __restrict__ ws, float* __restrict__ out) {
    int t = blockIdx.x * 256 + threadIdx.x;
    if (t < 1536) ws[t] = 0.f;
    if (t == 0) out[0] = 0.f;
}

__device__ __forceinline__ void softmax_col(const float* __restrict__ Z, int N, int i,
                                            float* z) {
    float m = -1e30f;
#pragma unroll
    for (int k = 0; k < KD; k++) { z[k] = Z[k * N + i]; m = fmaxf(m, z[k]); }
    float s = 0.f;
#pragma unroll
    for (int k = 0; k < KD; k++) { z[k] = fexp2((z[k] - m) * LOG2E); s += z[k]; }
    float inv = frcp(s);
#pragma unroll
    for (int k = 0; k < KD; k++) z[k] *= inv;
}

// ---- colsum[k] = sum_i softmax(Z)[k,i] * sigmoid(G[i,k]) ----
__device__ void colsum_pass(const float* __restrict__ Z, const float* __restrict__ G,
                            float* __restrict__ colsum, int N, int blk) {
    int i = blk * 256 + threadIdx.x;
    float z[KD];
    if (i < N) {
        softmax_col(Z, N, i, z);
#pragma unroll
        for (int k = 0; k < KD; k++) z[k] *= fsig(G[i * KD + k]);
    } else {
#pragma unroll
        for (int k = 0; k < KD; k++) z[k] = 0.f;
    }
    __shared__ float part[KD][4];
    int lane = threadIdx.x & 63, wv = threadIdx.x >> 6;
#pragma unroll
    for (int k = 0; k < KD; k++) {
        float v = z[k];
        for (int o = 32; o > 0; o >>= 1) v += __shfl_down(v, o);
        if (lane == 0) part[k][wv] = v;
    }
    __syncthreads();
    if (threadIdx.x < KD) {
        float v = part[threadIdx.x][0] + part[threadIdx.x][1] +
                  part[threadIdx.x][2] + part[threadIdx.x][3];
        atomicAdd(&colsum[threadIdx.x], v);
    }
}

// ---- ZCraw[a,b] = sum_s z[a,s] * (z[b,s]*sig(g[s,b]))  (64 samples/block) ----
__device__ void zc_pass(const float* __restrict__ Z, const float* __restrict__ G,
                        const int* __restrict__ samp, float* __restrict__ zcraw,
                        int N, int blk) {
    __shared__ float zb[64][KD + 1];
    __shared__ float zs[64][KD + 1];
    int tid = threadIdx.x;
    if (tid < 64) {
        int idx = samp[blk * 64 + tid];
        float z[KD];
        softmax_col(Z, N, idx, z);
#pragma unroll
        for (int k = 0; k < KD; k++) {
            zb[tid][k] = z[k];
            zs[tid][k] = z[k] * fsig(G[idx * KD + k]);
        }
    }
    __syncthreads();
    for (int p = tid; p < KD * KD; p += 256) {
        int a = p / KD, bb = p % KD;
        float acc = 0.f;
#pragma unroll 8
        for (int s = 0; s < 64; s++) acc += zb[s][a] * zs[s][bb];
        atomicAdd(&zcraw[p], acc);
    }
}

__global__ void __launch_bounds__(256) k_s1(const float* __restrict__ Zi,
                                            const float* __restrict__ Zj,
                                            const float* __restrict__ Gi,
                                            const float* __restrict__ Gj,
                                            const int* __restrict__ si,
                                            const int* __restrict__ sj,
                                            float* __restrict__ ws) {
    int b = blockIdx.x;
    if (b < NBI)                  colsum_pass(Zi, Gi, ws + W_CSI, NI, b);
    else if (b < NBI + NBJ)       colsum_pass(Zj, Gj, ws + W_CSJ, NJ, b - NBI);
    else if (b < NBI + NBJ + NZI) zc_pass(Zi, Gi, si, ws + W_ZCI, NI, b - NBI - NBJ);
    else                          zc_pass(Zj, Gj, sj, ws + W_ZCJ, NJ, b - NBI - NBJ - NZI);
}

// ---- per-node point + packed side data ----
__global__ void __launch_bounds__(256) k_pa(const float* __restrict__ Zi,
                                            const float* __restrict__ Zj,
                                            const float* __restrict__ beta,
                                            const float* __restrict__ gamma,
                                            const float* __restrict__ Ai,
                                            const float* __restrict__ Aj,
                                            float* __restrict__ ws) {
    __shared__ float azc[64];
    int b = blockIdx.x;
    bool isI = b < NBI;
    const float* A  = isI ? Ai : Aj;
    const float* ZC = ws + (isI ? W_ZCI : W_ZCJ);
    const float* CS = ws + (isI ? W_CSI : W_CSJ);
    if (threadIdx.x < 2 * KD) {
        int d = threadIdx.x / KD, c = threadIdx.x % KD;
        float acc = 0.f;
#pragma unroll
        for (int a = 0; a < KD; a++) acc += A[d * KD + a] * ZC[a * KD + c];
        azc[threadIdx.x] = acc * frcp(CS[c]);
    }
    __syncthreads();
    const float* Z = isI ? Zi : Zj;
    int N = isI ? NI : NJ;
    int i = (isI ? b : b - NBI) * 256 + threadIdx.x;
    if (i < N) {
        float z[KD];
        softmax_col(Z, N, i, z);
        float x = 0.f, y = 0.f;
#pragma unroll
        for (int k = 0; k < KD; k++) { x = fmaf(azc[k], z[k], x); y = fmaf(azc[KD + k], z[k], y); }
        float4* Q = (float4*)(ws + (isI ? W_QI : W_QJ));
        if (isI) Q[i] = make_float4(x, y, beta[i], 0.f);
        else     Q[i] = make_float4(x - EPSC, y - EPSC, beta[i], gamma[i]);
    }
}

__device__ __forceinline__ void block_sum_atomic(float v, float* dst, float scale) {
    __shared__ float part[4];
    int lane = threadIdx.x & 63, wv = threadIdx.x >> 6;
#pragma unroll
    for (int o = 32; o > 0; o >>= 1) v += __shfl_down(v, o);
    if (lane == 0) part[wv] = v;
    __syncthreads();
    if (threadIdx.x == 0)
        atomicAdd(dst, scale * (part[0] + part[1] + part[2] + part[3]));
}

// out[0] accumulates z_pdist2 - HALF_E2 * (dense - diag) directly
__global__ void __launch_bounds__(256) k_sums(const int* __restrict__ si,
                                              const int* __restrict__ sj,
                                              const int* __restrict__ spi,
                                              const int* __restrict__ spj,
                                              const float* __restrict__ ws,
                                              float* __restrict__ out) {
    const float4* Qi = (const float4*)(ws + W_QI);
    const float4* Qj = (const float4*)(ws + W_QJ);
    int b = blockIdx.x, tid = threadIdx.x;
    if (b < NDB) {
        // dense 16 rows x 2048 cols; exp(b+g-d) = e^b * (e^g * 2^(-d*log2e))
        __shared__ float rx[16], ry[16], rez[16];
        int r0 = (b >> 1) * 16, c0 = (b & 1) * 2048;
        if (tid < 16) {
            float4 R = Qi[si[r0 + tid]];
            rx[tid] = R.x; ry[tid] = R.y; rez[tid] = fexp2(R.z * LOG2E);
        }
        float cx[8], cy[8], ej[8];
#pragma unroll
        for (int q = 0; q < 8; q++) {
            float4 p = Qj[sj[c0 + q * 256 + tid]];
            cx[q] = p.x; cy[q] = p.y; ej[q] = fexp2(p.w * LOG2E);
        }
        __syncthreads();
        float acc = 0.f;
        for (int r = 0; r < 16; r++) {
            float px = rx[r], py = ry[r];
            float accr = 0.f;
#pragma unroll
            for (int q = 0; q < 8; q++) {
                float dx = px - cx[q];
                float dy = py - cy[q];
                float d2 = fmaf(dy, dy, dx * dx);
                float dist = fsqrt(d2);
                accr = fmaf(ej[q], fexp2(-LOG2E * dist), accr);
            }
            acc = fmaf(rez[r], accr, acc);
        }
        block_sum_atomic(acc, out, -HALF_E2);
    } else if (b < NDB + NSB) {
        int g4 = (b - NDB) * 256 + tid;
        float acc = 0.f;
        if (g4 < NE / 4) {
            int4 ia = ((const int4*)spi)[g4];
            int4 ja = ((const int4*)spj)[g4];
            float4 a0 = Qi[ia.x], a1 = Qi[ia.y], a2 = Qi[ia.z], a3 = Qi[ia.w];
            float4 b0 = Qj[ja.x], b1 = Qj[ja.y], b2 = Qj[ja.z], b3 = Qj[ja.w];
            float dx, dy;
            dx = a0.x - b0.x; dy = a0.y - b0.y;
            acc += a0.z + b0.z - fsqrt(fmaf(dy, dy, dx * dx));
            dx = a1.x - b1.x; dy = a1.y - b1.y;
            acc += a1.z + b1.z - fsqrt(fmaf(dy, dy, dx * dx));
            dx = a2.x - b2.x; dy = a2.y - b2.y;
            acc += a2.z + b2.z - fsqrt(fmaf(dy, dy, dx * dx));
            dx = a3.x - b3.x; dy = a3.y - b3.y;
            acc += a3.z + b3.z - fsqrt(fmaf(dy, dy, dx * dx));
        }
        block_sum_atomic(acc, out, 1.f);
    } else {
        // diagonal pairs (s,s): were zeroed in M, so add back
        int s = (b - NDB - NSB) * 256 + tid;
        float4 qi = Qi[si[s]];
        float4 qj = Qj[sj[s]];
        float dx = qi.x - qj.x, dy = qi.y - qj.y;
        float v = fexp2((qi.z + qj.w - fsqrt(fmaf(dy, dy, dx * dx))) * LOG2E);
        block_sum_atomic(v, out, HALF_E2);
    }
}

extern "C" void kernel_launch(void* const* d_in, const int* in_sizes, int n_in,
                              void* d_out, int out_size, void* d_ws, size_t ws_size,
                              hipStream_t stream) {
    const float* beta  = (const float*)d_in[0];
    const float* gamma = (const float*)d_in[1];
    const float* Ai    = (const float*)d_in[2];
    const float* Aj    = (const float*)d_in[3];
    const float* Zi    = (const float*)d_in[4];
    const float* Zj    = (const float*)d_in[5];
    const float* Gi    = (const float*)d_in[6];
    const float* Gj    = (const float*)d_in[7];
    const int* si  = (const int*)d_in[8];
    const int* sj  = (const int*)d_in[9];
    const int* spi = (const int*)d_in[10];
    const int* spj = (const int*)d_in[11];
    float* ws  = (float*)d_ws;
    float* out = (float*)d_out;

    k_init<<<6, 256, 0, stream>>>(ws, out);
    k_s1<<<NBI + NBJ + NZI + NZJ, 256, 0, stream>>>(Zi, Zj, Gi, Gj, si, sj, ws);
    k_pa<<<NBI + NBJ, 256, 0, stream>>>(Zi, Zj, beta, gamma, Ai, Aj, ws);
    k_sums<<<NDB + NSB + NGB, 256, 0, stream>>>(si, sj, spi, spj, ws, out);
}

// Round 4
// 52.746 us; speedup vs baseline: 1.9589x; 1.3643x over previous
//
#include <hip/hip_runtime.h>

#define NI 100000
#define NJ 50000
#define KD 25
#define SI 8192
#define SJ 4096
#define NE 1000000
#define EPSC 1e-6f
#define LOG2E 1.4426950408889634f
#define HALF_E2 3.6945280494653252f   // 0.5 * e * e

#define NBI ((NI + 255) / 256)   // 391
#define NBJ ((NJ + 255) / 256)   // 196
#define NZI (SI / 64)            // 128
#define NZJ (SJ / 64)            // 64
#define NPK ((SI + SJ) / 256)    // 48 pack blocks
#define NDB 1024                 // dense: 512 row-groups x 2 col-halves
#define NSB 1024                 // sparse
#define NGB 16                   // diag

// workspace layout (float offsets)
#define W_CSI 0                  // 8 copies x 32
#define W_CSJ 256                // 8 copies x 32
#define W_ZCI 512                // 2 copies x 640
#define W_ZCJ 1792               // 2 copies x 640
#define W_PART 3072              // 128 partial slots
#define W_QI 4096                // float4[NI]  (x, y, beta, 0)
#define W_QJ (W_QI + 4 * NI)     // float4[NJ]  (x-eps, y-eps, beta, gamma)
#define W_QSI (W_QJ + 4 * NJ)    // float4[SI]  (x, y, e^beta, 0)
#define W_QSJ (W_QSI + 4 * SI)   // float4[SJ]  (x-eps, y-eps, e^gamma, 0)

__device__ __forceinline__ float fexp2(float x) { return __builtin_amdgcn_exp2f(x); }
__device__ __forceinline__ float fsqrt(float x) { return __builtin_amdgcn_sqrtf(x); }
__device__ __forceinline__ float frcp(float x)  { return __builtin_amdgcn_rcpf(x); }
__device__ __forceinline__ float fsig(float g)  { return frcp(1.f + fexp2(-g * LOG2E)); }

__global__ void k_init(float* __restrict__ ws, float* __restrict__ out) {
    int t = blockIdx.x * 256 + threadIdx.x;
    if (t < 3200) ws[t] = 0.f;
    if (t == 0) out[0] = 0.f;
}

__device__ __forceinline__ void softmax_col(const float* __restrict__ Z, int N, int i,
                                            float* z) {
    float m = -1e30f;
#pragma unroll
    for (int k = 0; k < KD; k++) { z[k] = Z[k * N + i]; m = fmaxf(m, z[k]); }
    float s = 0.f;
#pragma unroll
    for (int k = 0; k < KD; k++) { z[k] = fexp2((z[k] - m) * LOG2E); s += z[k]; }
    float inv = frcp(s);
#pragma unroll
    for (int k = 0; k < KD; k++) z[k] *= inv;
}

// ---- colsum[k] = sum_i softmax(Z)[k,i] * sigmoid(G[i,k]), 8 spread copies ----
__device__ void colsum_pass(const float* __restrict__ Z, const float* __restrict__ G,
                            float* __restrict__ colsum, int N, int blk) {
    int i = blk * 256 + threadIdx.x;
    float z[KD];
    if (i < N) {
        softmax_col(Z, N, i, z);
#pragma unroll
        for (int k = 0; k < KD; k++) z[k] *= fsig(G[i * KD + k]);
    } else {
#pragma unroll
        for (int k = 0; k < KD; k++) z[k] = 0.f;
    }
    __shared__ float part[KD][4];
    int lane = threadIdx.x & 63, wv = threadIdx.x >> 6;
#pragma unroll
    for (int k = 0; k < KD; k++) {
        float v = z[k];
        for (int o = 32; o > 0; o >>= 1) v += __shfl_down(v, o);
        if (lane == 0) part[k][wv] = v;
    }
    __syncthreads();
    if (threadIdx.x < KD) {
        float v = part[threadIdx.x][0] + part[threadIdx.x][1] +
                  part[threadIdx.x][2] + part[threadIdx.x][3];
        atomicAdd(&colsum[((blk & 7) << 5) + threadIdx.x], v);
    }
}

// ---- ZCraw[a,b] = sum_s z[a,s] * (z[b,s]*sig(g[s,b])), 2 spread copies ----
__device__ void zc_pass(const float* __restrict__ Z, const float* __restrict__ G,
                        const int* __restrict__ samp, float* __restrict__ zcraw,
                        int N, int blk) {
    __shared__ float zb[64][KD + 1];
    __shared__ float zs[64][KD + 1];
    int tid = threadIdx.x;
    if (tid < 64) {
        int idx = samp[blk * 64 + tid];
        float z[KD];
        softmax_col(Z, N, idx, z);
#pragma unroll
        for (int k = 0; k < KD; k++) {
            zb[tid][k] = z[k];
            zs[tid][k] = z[k] * fsig(G[idx * KD + k]);
        }
    }
    __syncthreads();
    for (int p = tid; p < KD * KD; p += 256) {
        int a = p / KD, bb = p % KD;
        float acc = 0.f;
#pragma unroll 8
        for (int s = 0; s < 64; s++) acc += zb[s][a] * zs[s][bb];
        atomicAdd(&zcraw[(blk & 1) * 640 + p], acc);
    }
}

__global__ void __launch_bounds__(256) k_s1(const float* __restrict__ Zi,
                                            const float* __restrict__ Zj,
                                            const float* __restrict__ Gi,
                                            const float* __restrict__ Gj,
                                            const int* __restrict__ si,
                                            const int* __restrict__ sj,
                                            float* __restrict__ ws) {
    int b = blockIdx.x;
    if (b < NBI)                  colsum_pass(Zi, Gi, ws + W_CSI, NI, b);
    else if (b < NBI + NBJ)       colsum_pass(Zj, Gj, ws + W_CSJ, NJ, b - NBI);
    else if (b < NBI + NBJ + NZI) zc_pass(Zi, Gi, si, ws + W_ZCI, NI, b - NBI - NBJ);
    else                          zc_pass(Zj, Gj, sj, ws + W_ZCJ, NJ, b - NBI - NBJ - NZI);
}

// ---- per-node point + packed side data ----
__global__ void __launch_bounds__(256) k_pa(const float* __restrict__ Zi,
                                            const float* __restrict__ Zj,
                                            const float* __restrict__ beta,
                                            const float* __restrict__ gamma,
                                            const float* __restrict__ Ai,
                                            const float* __restrict__ Aj,
                                            float* __restrict__ ws) {
    __shared__ float azc[64];
    int b = blockIdx.x;
    bool isI = b < NBI;
    const float* A  = isI ? Ai : Aj;
    const float* ZC = ws + (isI ? W_ZCI : W_ZCJ);
    const float* CS = ws + (isI ? W_CSI : W_CSJ);
    if (threadIdx.x < 2 * KD) {
        int d = threadIdx.x / KD, c = threadIdx.x % KD;
        float acc = 0.f;
#pragma unroll
        for (int a = 0; a < KD; a++)
            acc += A[d * KD + a] * (ZC[a * KD + c] + ZC[640 + a * KD + c]);
        float cs = 0.f;
#pragma unroll
        for (int r = 0; r < 8; r++) cs += CS[(r << 5) + c];
        azc[threadIdx.x] = acc * frcp(cs);
    }
    __syncthreads();
    const float* Z = isI ? Zi : Zj;
    int N = isI ? NI : NJ;
    int i = (isI ? b : b - NBI) * 256 + threadIdx.x;
    if (i < N) {
        float z[KD];
        softmax_col(Z, N, i, z);
        float x = 0.f, y = 0.f;
#pragma unroll
        for (int k = 0; k < KD; k++) { x = fmaf(azc[k], z[k], x); y = fmaf(azc[KD + k], z[k], y); }
        float4* Q = (float4*)(ws + (isI ? W_QI : W_QJ));
        if (isI) Q[i] = make_float4(x, y, beta[i], 0.f);
        else     Q[i] = make_float4(x - EPSC, y - EPSC, beta[i], gamma[i]);
    }
}

// ---- gather sampled rows/cols into contiguous arrays, precompute exps ----
__global__ void __launch_bounds__(256) k_pack(const int* __restrict__ si,
                                              const int* __restrict__ sj,
                                              float* __restrict__ ws) {
    int t = blockIdx.x * 256 + threadIdx.x;
    const float4* Qi = (const float4*)(ws + W_QI);
    const float4* Qj = (const float4*)(ws + W_QJ);
    float4* QSI = (float4*)(ws + W_QSI);
    float4* QSJ = (float4*)(ws + W_QSJ);
    if (t < SI) {
        float4 q = Qi[si[t]];
        QSI[t] = make_float4(q.x, q.y, fexp2(q.z * LOG2E), 0.f);
    } else if (t < SI + SJ) {
        int s = t - SI;
        float4 q = Qj[sj[s]];
        QSJ[s] = make_float4(q.x, q.y, fexp2(q.w * LOG2E), 0.f);
    }
}

__device__ __forceinline__ void block_part_atomic(float v, float* __restrict__ ws,
                                                  int b, float scale) {
    __shared__ float part[4];
    int lane = threadIdx.x & 63, wv = threadIdx.x >> 6;
#pragma unroll
    for (int o = 32; o > 0; o >>= 1) v += __shfl_down(v, o);
    if (lane == 0) part[wv] = v;
    __syncthreads();
    if (threadIdx.x == 0)
        atomicAdd(&ws[W_PART + (b & 127)], scale * (part[0] + part[1] + part[2] + part[3]));
}

__global__ void __launch_bounds__(256) k_sums(const int* __restrict__ spi,
                                              const int* __restrict__ spj,
                                              float* __restrict__ ws) {
    const float4* Qi  = (const float4*)(ws + W_QI);
    const float4* Qj  = (const float4*)(ws + W_QJ);
    const float4* QSI = (const float4*)(ws + W_QSI);
    const float4* QSJ = (const float4*)(ws + W_QSJ);
    int b = blockIdx.x, tid = threadIdx.x;
    if (b < NDB) {
        // dense 16 rows x 2048 cols; exp(b+g-d) = e^b * (e^g * 2^(-d*log2e))
        __shared__ float rx[16], ry[16], re[16];
        int r0 = (b >> 1) * 16, c0 = (b & 1) * 2048;
        if (tid < 16) {
            float4 R = QSI[r0 + tid];
            rx[tid] = R.x; ry[tid] = R.y; re[tid] = R.z;
        }
        float cx[8], cy[8], ce[8];
#pragma unroll
        for (int q = 0; q < 8; q++) {
            float4 p = QSJ[c0 + q * 256 + tid];
            cx[q] = p.x; cy[q] = p.y; ce[q] = p.z;
        }
        __syncthreads();
        float acc = 0.f;
        for (int r = 0; r < 16; r++) {
            float px = rx[r], py = ry[r];
            float accr = 0.f;
#pragma unroll
            for (int q = 0; q < 8; q++) {
                float dx = px - cx[q];
                float dy = py - cy[q];
                float dist = fsqrt(fmaf(dy, dy, dx * dx));
                accr = fmaf(ce[q], fexp2(-LOG2E * dist), accr);
            }
            acc = fmaf(re[r], accr, acc);
        }
        block_part_atomic(acc, ws, b, -HALF_E2);
    } else if (b < NDB + NSB) {
        int g4 = (b - NDB) * 256 + tid;
        float acc = 0.f;
        if (g4 < NE / 4) {
            int4 ia = ((const int4*)spi)[g4];
            int4 ja = ((const int4*)spj)[g4];
            float4 a0 = Qi[ia.x], a1 = Qi[ia.y], a2 = Qi[ia.z], a3 = Qi[ia.w];
            float4 b0 = Qj[ja.x], b1 = Qj[ja.y], b2 = Qj[ja.z], b3 = Qj[ja.w];
            float dx, dy;
            dx = a0.x - b0.x; dy = a0.y - b0.y;
            acc += a0.z + b0.z - fsqrt(fmaf(dy, dy, dx * dx));
            dx = a1.x - b1.x; dy = a1.y - b1.y;
            acc += a1.z + b1.z - fsqrt(fmaf(dy, dy, dx * dx));
            dx = a2.x - b2.x; dy = a2.y - b2.y;
            acc += a2.z + b2.z - fsqrt(fmaf(dy, dy, dx * dx));
            dx = a3.x - b3.x; dy = a3.y - b3.y;
            acc += a3.z + b3.z - fsqrt(fmaf(dy, dy, dx * dx));
        }
        block_part_atomic(acc, ws, b, 1.f);
    } else {
        // diagonal pairs (s,s): zeroed in M, add back
        int s = (b - NDB - NSB) * 256 + tid;
        float4 a = QSI[s];
        float4 c = QSJ[s];
        float dx = a.x - c.x, dy = a.y - c.y;
        float v = a.z * c.z * fexp2(-LOG2E * fsqrt(fmaf(dy, dy, dx * dx)));
        block_part_atomic(v, ws, b, HALF_E2);
    }
}

__global__ void k_fin(const float* __restrict__ ws, float* __restrict__ out) {
    __shared__ float w2[2];
    int tid = threadIdx.x;   // 128 threads
    float v = ws[W_PART + tid];
#pragma unroll
    for (int o = 32; o > 0; o >>= 1) v += __shfl_down(v, o);
    if ((tid & 63) == 0) w2[tid >> 6] = v;
    __syncthreads();
    if (tid == 0) out[0] = w2[0] + w2[1];
}

extern "C" void kernel_launch(void* const* d_in, const int* in_sizes, int n_in,
                              void* d_out, int out_size, void* d_ws, size_t ws_size,
                              hipStream_t stream) {
    const float* beta  = (const float*)d_in[0];
    const float* gamma = (const float*)d_in[1];
    const float* Ai    = (const float*)d_in[2];
    const float* Aj    = (const float*)d_in[3];
    const float* Zi    = (const float*)d_in[4];
    const float* Zj    = (const float*)d_in[5];
    const float* Gi    = (const float*)d_in[6];
    const float* Gj    = (const float*)d_in[7];
    const int* si  = (const int*)d_in[8];
    const int* sj  = (const int*)d_in[9];
    const int* spi = (const int*)d_in[10];
    const int* spj = (const int*)d_in[11];
    float* ws  = (float*)d_ws;
    float* out = (float*)d_out;

    k_init<<<13, 256, 0, stream>>>(ws, out);
    k_s1<<<NBI + NBJ + NZI + NZJ, 256, 0, stream>>>(Zi, Zj, Gi, Gj, si, sj, ws);
    k_pa<<<NBI + NBJ, 256, 0, stream>>>(Zi, Zj, beta, gamma, Ai, Aj, ws);
    k_pack<<<NPK, 256, 0, stream>>>(si, sj, ws);
    k_sums<<<NDB + NSB + NGB, 256, 0, stream>>>(spi, spj, ws);
    k_fin<<<1, 128, 0, stream>>>(ws, out);
}